// Round 16
// baseline (413.492 us; speedup 1.0000x reference)
//
#include <hip/hip_runtime.h>
#include <hip/hip_bf16.h>

#define NN 16384
#define DD 128
#define BK 64          // k floats per pipeline stage (enc kernel)
#define NT (NN / BK)   // 256 stages (enc kernel)
#define NT2 (NN / 128) // 128 stages (fp8 kernel)

typedef __attribute__((ext_vector_type(8))) short short8;
typedef __attribute__((ext_vector_type(4))) float f32x4;
typedef __attribute__((ext_vector_type(2))) unsigned u32x2;

__device__ __forceinline__ short f2bf(float f) {
  union { float f; unsigned u; } v; v.f = f;
  unsigned r = v.u + 0x7fffu + ((v.u >> 16) & 1u);   // RNE f32->bf16
  return (short)(r >> 16);
}
// f32 (a>=0) -> e4m3 byte of a*4096 (bias fold: -108), RNE, FTZ
__device__ __forceinline__ unsigned enc8(float f) {
  unsigned u = __float_as_uint(f);
  u += 0x7FFFFu + ((u >> 20) & 1u);
  int e8 = (int)(u >> 23) - 108;
  return e8 > 0 ? (unsigned)((e8 << 3) | ((u >> 20) & 7u)) : 0u;
}
// e4m3 byte -> bf16 bits: (b<<4) + (108<<7), 0 stays 0
__device__ __forceinline__ short dec8(unsigned b) {
  return b ? (short)((b << 4) + 0x3600) : (short)0;
}

#define WAITV(n) asm volatile("s_waitcnt vmcnt(" #n ")" ::: "memory")
#define BAR()    do { __builtin_amdgcn_s_barrier(); asm volatile("" ::: "memory"); } while (0)

// ---------------------------------------------------------------------------
// small GEMM: T0 = X @ W0, B-fragment-major output (as before)
// ---------------------------------------------------------------------------
__global__ __launch_bounds__(256, 1)
void small_gemm(const float* __restrict__ In_, const float* __restrict__ W,
                short* __restrict__ Tf)
{
  __shared__ float sW[DD * DD];
  const int tid = threadIdx.x;
  {
    const float4* W4 = (const float4*)W;
    float4* sW4 = (float4*)sW;
#pragma unroll
    for (int i = 0; i < 16; ++i) sW4[tid + 256 * i] = W4[tid + 256 * i];
  }
  __syncthreads();

  const int k0 = blockIdx.x * 16;
  const int kk = tid & 15;
  const int q  = tid >> 4;
  const long rowoff = (long)(k0 + kk) * DD;

  float acc[8] = {0.f, 0.f, 0.f, 0.f, 0.f, 0.f, 0.f, 0.f};
  const float4* In4 = (const float4*)(In_ + rowoff);
  for (int j4 = 0; j4 < 32; ++j4) {
    float4 a4 = In4[j4];
    float av[4] = {a4.x, a4.y, a4.z, a4.w};
#pragma unroll
    for (int c = 0; c < 4; ++c)
#pragma unroll
      for (int dd = 0; dd < 8; ++dd)
        acc[dd] += av[c] * sW[(j4 * 4 + c) * DD + q * 8 + dd];
  }

  const int k    = k0 + kk;
  const int kt   = k >> 5;
  const int ksub = (k >> 3) & 3;
  const int e    = k & 7;
#pragma unroll
  for (int dd = 0; dd < 8; ++dd) {
    const int d  = q * 8 + dd;
    const int dt = d >> 4;
    const int lf = (d & 15) | (ksub << 4);
    Tf[((((long)kt * 8) + dt) * 64 + lf) * 8 + e] = f2bf(acc[dd]);
  }
}

// ---------------------------------------------------------------------------
// FUSED agg layer 1 + fp8 A side-write (8-wave, R15 structure):
//   T1f = frag(relu(A @ T0) @ W1);  A8[kt][rtg][lane][8B] = e4m3(A*4096)
// Wave (rw=w&3, dh=w>>2): rows rw*16..+15, dt-half dh; encodes ks=dh only
// -> uniform 1 store/phase/wave. vmcnt: peel 8/9/10, steady 11, drain 11/7/3.
// ---------------------------------------------------------------------------
__global__ __launch_bounds__(512, 1)
void agg_fused_enc(const float* __restrict__ A, const short* __restrict__ Bf,
                   const float* __restrict__ W1, short* __restrict__ T1f,
                   char* __restrict__ A8)
{
  __shared__ __align__(16) char sMem[131072];    // A: 4x16KB | B: 4x16KB
  char* sA = sMem;
  char* sB = sMem + 65536;

  const int tid  = threadIdx.x;
  const int lane = tid & 63;
  const int w    = tid >> 6;
  const int rw   = w & 3;
  const int dh   = w >> 2;
  const long rb  = (long)blockIdx.x * 64;
  const int arow = lane & 15;
  const int kgrp = lane >> 4;
  const long rtg = (long)blockIdx.x * 4 + rw;

  int rowi[2], colfi[2];
#pragma unroll
  for (int i = 0; i < 2; ++i) {
    const int o  = (2 * w + i) * 1024 + lane * 16;
    const int rr = o >> 8;
    const int cb = (o & 255) ^ ((rr & 7) << 4);
    rowi[i] = rr;
    colfi[i] = cb >> 2;
  }

  f32x4 acc[4];
#pragma unroll
  for (int j = 0; j < 4; ++j) acc[j] = (f32x4){0.f, 0.f, 0.f, 0.f};

  auto STAGE = [&](int buf, int t) {
#pragma unroll
    for (int i = 0; i < 2; ++i) {
      const float* g = A + (rb + rowi[i]) * (long)NN + t * BK + colfi[i];
      __builtin_amdgcn_global_load_lds(
          (const __attribute__((address_space(1))) unsigned int*)g,
          (__attribute__((address_space(3))) unsigned int*)(sA + buf * 16384 + (2 * w + i) * 1024),
          16, 0, 0x12);
    }
#pragma unroll
    for (int i = 0; i < 2; ++i) {
      const short* g = Bf + (long)t * 8192 + (2 * w + i) * 512 + lane * 8;
      __builtin_amdgcn_global_load_lds(
          (const __attribute__((address_space(1))) unsigned int*)g,
          (__attribute__((address_space(3))) unsigned int*)(sB + buf * 16384 + (2 * w + i) * 1024),
          16, 0, 0);
    }
  };

  auto COMPUTE = [&](int buf, int p) {
    const char* la = sA + buf * 16384;
    const char* lb = sB + buf * 16384 + lane * 16;
    const int row = rw * 16 + arow;
    const int sw  = (arow & 7) << 4;
#pragma unroll
    for (int ks = 0; ks < 2; ++ks) {
      f32x4 a0 = *(const f32x4*)(la + row * 256 + ((ks * 128 + kgrp * 32) ^ sw));
      f32x4 a1 = *(const f32x4*)(la + row * 256 + ((ks * 128 + kgrp * 32 + 16) ^ sw));
      if (ks == dh) {       // wave-uniform: exactly one store per wave per phase
        u32x2 pk;
        pk[0] = enc8(a0.x) | (enc8(a0.y) << 8) | (enc8(a0.z) << 16) | (enc8(a0.w) << 24);
        pk[1] = enc8(a1.x) | (enc8(a1.y) << 8) | (enc8(a1.z) << 16) | (enc8(a1.w) << 24);
        __builtin_nontemporal_store(pk,
            (u32x2*)(A8 + (((long)(2 * p + dh) * 1024 + rtg) * 512) + lane * 8));
      }
      short8 af;
      af[0] = f2bf(a0.x); af[1] = f2bf(a0.y); af[2] = f2bf(a0.z); af[3] = f2bf(a0.w);
      af[4] = f2bf(a1.x); af[5] = f2bf(a1.y); af[6] = f2bf(a1.z); af[7] = f2bf(a1.w);
#pragma unroll
      for (int j = 0; j < 4; ++j) {
        short8 bf = *(const short8*)(lb + (ks * 8 + dh * 4 + j) * 1024);
        acc[j] = __builtin_amdgcn_mfma_f32_16x16x32_bf16(af, bf, acc[j], 0, 0, 0);
      }
    }
  };

  STAGE(0, 0); STAGE(1, 1); STAGE(2, 2);

  // peeled phases 0..2 (store count ramps up)
  WAITV(8);  BAR(); STAGE(3, 3); COMPUTE(0, 0);
  WAITV(9);  BAR(); STAGE(0, 4); COMPUTE(1, 1);
  WAITV(10); BAR(); STAGE(1, 5); COMPUTE(2, 2);
  for (int p = 3; p < NT - 3; ++p) {
    WAITV(11); BAR(); STAGE((p + 3) & 3, p + 3); COMPUTE(p & 3, p);
  }
  WAITV(11); BAR(); COMPUTE((NT - 3) & 3, NT - 3);
  WAITV(7);  BAR(); COMPUTE((NT - 2) & 3, NT - 2);
  WAITV(3);  BAR(); COMPUTE((NT - 1) & 3, NT - 1);

  // ===== fused epilogue: T1 tile = relu(acc) @ W1 (unchanged from R15) =====
  char* tbuf = sMem + rw * 4096;
#pragma unroll
  for (int j = 0; j < 4; ++j) {
#pragma unroll
    for (int r = 0; r < 4; ++r) {
      float v = acc[j][r];
      v = v > 0.f ? v : 0.f;
      const int rowl = kgrp * 4 + r;
      const int col  = (dh * 4 + j) * 16 + arow;
      const int byte = (rowl * 256 + col * 2) ^ ((rowl & 15) << 4);
      *(short*)(tbuf + byte) = f2bf(v);
    }
  }
  __syncthreads();

  {
    short* W1fL = (short*)(sMem + 98304);
    const float4* W14 = (const float4*)W1;
    for (int it = 0; it < 8; ++it) {
      const int lin = tid + it * 512;
      const int j  = lin >> 5;
      const int d4 = lin & 31;
      float4 wv = W14[j * 32 + d4];
      float wa[4] = {wv.x, wv.y, wv.z, wv.w};
      const int ks = j >> 5, ksub = (j >> 3) & 3, e = j & 7;
#pragma unroll
      for (int c = 0; c < 4; ++c) {
        const int d = d4 * 4 + c;
        const int dt = d >> 4;
        const int lf = (d & 15) | (ksub << 4);
        W1fL[((ks * 8 + dt) * 64 + lf) * 8 + e] = f2bf(wa[c]);
      }
    }
  }
  __syncthreads();

  f32x4 nacc[4];
#pragma unroll
  for (int j = 0; j < 4; ++j) nacc[j] = (f32x4){0.f, 0.f, 0.f, 0.f};
  {
    const short* W1fL = (const short*)(sMem + 98304);
#pragma unroll
    for (int ks = 0; ks < 4; ++ks) {
      short8 af = *(const short8*)(tbuf +
          ((arow * 256 + (ks * 32 + kgrp * 8) * 2) ^ ((arow & 15) << 4)));
#pragma unroll
      for (int j = 0; j < 4; ++j) {
        short8 wf = *(const short8*)&W1fL[((ks * 8 + dh * 4 + j) * 64 + lane) * 8];
        nacc[j] = __builtin_amdgcn_mfma_f32_16x16x32_bf16(af, wf, nacc[j], 0, 0, 0);
      }
    }
  }

  char* obuf = sMem + 65536 + (rw >> 1) * 8192;
  const int kh = rw & 1;
#pragma unroll
  for (int j = 0; j < 4; ++j) {
#pragma unroll
    for (int r = 0; r < 4; ++r) {
      const int dt = dh * 4 + j;
      const int kl = kh * 16 + kgrp * 4 + r;
      const int lf = arow | ((kl >> 3) << 4);
      const int e  = kl & 7;
      *(short*)(obuf + (dt * 512 + lf * 8 + e) * 2) = f2bf(nacc[j][r]);
    }
  }
  __syncthreads();
  {
    const long ktg = (long)blockIdx.x * 2 + (w >> 2);
    const char* obr = sMem + 65536 + ((w >> 2) & 1) * 8192;
#pragma unroll
    for (int i = 0; i < 2; ++i) {
      const int dt = (w & 3) * 2 + i;
      short8 vv = *(const short8*)(obr + (dt * 512 + lane * 8) * 2);
      *(short8*)(T1f + ((ktg * 8 + dt) * 64 + lane) * 8) = vv;
    }
  }
}

// ---------------------------------------------------------------------------
// agg layer 2 from fp8 A (8-wave, BK=128 -> 128 phases):
//   out = relu(dec(A8) @ T1).  A8 read = 268 MB (vs 1074 MB fp32).
// Per phase: A8 8 KB (1 gll/wave, segs [kt=w>>1][rtpair=w&1]) +
//            B 32 KB (4 gll/wave) -> uniform 5 VMEM/wave/phase, WAITV(5).
// 3 bufs x 40 KB LDS, distance 2.
// ---------------------------------------------------------------------------
__global__ __launch_bounds__(512, 1)
void agg_fp8(const char* __restrict__ A8, const short* __restrict__ Bf,
             float* __restrict__ out_)
{
  __shared__ __align__(16) char sMem[3 * 40960];   // 120 KB

  const int tid  = threadIdx.x;
  const int lane = tid & 63;
  const int w    = tid >> 6;
  const int rw   = w & 3;
  const int dh   = w >> 2;
  const long rb  = (long)blockIdx.x * 64;
  const int arow = lane & 15;
  const int kgrp = lane >> 4;

  f32x4 acc[4];
#pragma unroll
  for (int j = 0; j < 4; ++j) acc[j] = (f32x4){0.f, 0.f, 0.f, 0.f};

  auto STAGE = [&](int buf, int t) {
    char* base = sMem + buf * 40960;
    // A8: 1 KB seg: kt = w>>1 (of 4), rt-pair = w&1
    const char* ga = A8 + ((long)(4 * t + (w >> 1)) * 1024 +
                           blockIdx.x * 4 + (w & 1) * 2) * 512 + lane * 16;
    __builtin_amdgcn_global_load_lds(
        (const __attribute__((address_space(1))) unsigned int*)ga,
        (__attribute__((address_space(3))) unsigned int*)(base + w * 1024),
        16, 0, 0x12);
    // B: 4 x 1 KB linear segs
#pragma unroll
    for (int i = 0; i < 4; ++i) {
      const short* g = Bf + (long)t * 16384 + (w * 4 + i) * 512 + lane * 8;
      __builtin_amdgcn_global_load_lds(
          (const __attribute__((address_space(1))) unsigned int*)g,
          (__attribute__((address_space(3))) unsigned int*)(base + 8192 + (w * 4 + i) * 1024),
          16, 0, 0);
    }
  };

  auto COMPUTE = [&](int buf) {
    const char* la = sMem + buf * 40960;
    const char* lb = la + 8192 + lane * 16;
#pragma unroll
    for (int ks = 0; ks < 4; ++ks) {
      u32x2 ab = *(const u32x2*)(la + ks * 2048 + (rw >> 1) * 1024 +
                                 (rw & 1) * 512 + lane * 8);
      short8 af;
      af[0] = dec8(ab[0] & 255);         af[1] = dec8((ab[0] >> 8) & 255);
      af[2] = dec8((ab[0] >> 16) & 255); af[3] = dec8(ab[0] >> 24);
      af[4] = dec8(ab[1] & 255);         af[5] = dec8((ab[1] >> 8) & 255);
      af[6] = dec8((ab[1] >> 16) & 255); af[7] = dec8(ab[1] >> 24);
#pragma unroll
      for (int j = 0; j < 4; ++j) {
        short8 bf = *(const short8*)(lb + (ks * 8 + dh * 4 + j) * 1024);
        acc[j] = __builtin_amdgcn_mfma_f32_16x16x32_bf16(af, bf, acc[j], 0, 0, 0);
      }
    }
  };

  STAGE(0, 0); STAGE(1, 1);

  int cur = 0, stg = 2;
  for (int t = 0; t < NT2 - 2; ++t) {
    WAITV(5); BAR(); STAGE(stg, t + 2); COMPUTE(cur);
    cur = (cur == 2) ? 0 : cur + 1;
    stg = (stg == 2) ? 0 : stg + 1;
  }
  WAITV(5); BAR(); COMPUTE(cur); cur = (cur == 2) ? 0 : cur + 1;
  WAITV(0); BAR(); COMPUTE(cur);

  // epilogue: relu + fp32 store
#pragma unroll
  for (int j = 0; j < 4; ++j) {
#pragma unroll
    for (int r = 0; r < 4; ++r) {
      float v = acc[j][r];
      v = v > 0.f ? v : 0.f;
      const long row = rb + rw * 16 + kgrp * 4 + r;
      const int  col = (dh * 4 + j) * 16 + arow;
      __builtin_nontemporal_store(v, out_ + row * DD + col);
    }
  }
}

// ---------------------------------------------------------------------------
extern "C" void kernel_launch(void* const* d_in, const int* in_sizes, int n_in,
                              void* d_out, int out_size, void* d_ws, size_t ws_size,
                              hipStream_t stream)
{
  const float* A  = (const float*)d_in[0];   // [16384][16384]
  const float* X  = (const float*)d_in[1];   // [16384][128]
  const float* W0 = (const float*)d_in[2];   // [128][128]
  const float* W1 = (const float*)d_in[3];   // [128][128]

  short* T0f = (short*)d_ws;                 // bf16 fragment-major T0 (4 MB)
  short* T1f = T0f + (size_t)DD * NN;        // bf16 fragment-major T1 (4 MB)
  char*  A8  = (char*)(T1f + (size_t)DD * NN); // fp8 A fragment-major (256 MB)

  small_gemm<<<NN / 16, 256, 0, stream>>>(X, W0, T0f);
  agg_fused_enc<<<NN / 64, 512, 0, stream>>>(A, T0f, W1, T1f, A8);
  agg_fp8<<<NN / 64, 512, 0, stream>>>(A8, T1f, (float*)d_out);
}

// Round 17
// 399.514 us; speedup vs baseline: 1.0350x; 1.0350x over previous
//
#include <hip/hip_runtime.h>
#include <hip/hip_bf16.h>

#define NN 16384
#define DD 128
#define BK 64          // k floats per pipeline stage
#define NT (NN / BK)   // 256 stages

typedef __attribute__((ext_vector_type(8))) short short8;
typedef __attribute__((ext_vector_type(4))) float f32x4;

__device__ __forceinline__ short f2bf(float f) {
  union { float f; unsigned u; } v; v.f = f;
  unsigned r = v.u + 0x7fffu + ((v.u >> 16) & 1u);   // RNE f32->bf16
  return (short)(r >> 16);
}
__device__ __forceinline__ float bf2f(short s) {
  union { unsigned u; float f; } v; v.u = ((unsigned)(unsigned short)s) << 16;
  return v.f;
}

#define WAITV(n) asm volatile("s_waitcnt vmcnt(" #n ")" ::: "memory")
#define BAR()    do { __builtin_amdgcn_s_barrier(); asm volatile("" ::: "memory"); } while (0)

// ---------------------------------------------------------------------------
// small GEMM: T = X @ W0, written in MFMA B-fragment-major layout:
//   element (d, k):  kt=k>>5, dt=d>>4, lane=(d&15)|(((k>>3)&3)<<4), e=k&7
//   Tf[(((kt*8)+dt)*64 + lane)*8 + e]
// ---------------------------------------------------------------------------
__global__ __launch_bounds__(256, 1)
void small_gemm(const float* __restrict__ In_, const float* __restrict__ W,
                short* __restrict__ Tf)
{
  __shared__ float sW[DD * DD];   // 64 KB
  const int tid = threadIdx.x;
  {
    const float4* W4 = (const float4*)W;
    float4* sW4 = (float4*)sW;
#pragma unroll
    for (int i = 0; i < 16; ++i) sW4[tid + 256 * i] = W4[tid + 256 * i];
  }
  __syncthreads();

  const int k0 = blockIdx.x * 16;
  const int kk = tid & 15;        // k-row within tile
  const int q  = tid >> 4;        // d-chunk 0..15 -> d = 8q..8q+7
  const long rowoff = (long)(k0 + kk) * DD;

  float acc[8] = {0.f, 0.f, 0.f, 0.f, 0.f, 0.f, 0.f, 0.f};
  const float4* In4 = (const float4*)(In_ + rowoff);
  for (int j4 = 0; j4 < 32; ++j4) {
    float4 a4 = In4[j4];
    float av[4] = {a4.x, a4.y, a4.z, a4.w};
#pragma unroll
    for (int c = 0; c < 4; ++c)
#pragma unroll
      for (int dd = 0; dd < 8; ++dd)
        acc[dd] += av[c] * sW[(j4 * 4 + c) * DD + q * 8 + dd];
  }

  const int k    = k0 + kk;
  const int kt   = k >> 5;
  const int ksub = (k >> 3) & 3;
  const int e    = k & 7;
#pragma unroll
  for (int dd = 0; dd < 8; ++dd) {
    const int d  = q * 8 + dd;
    const int dt = d >> 4;
    const int lf = (d & 15) | (ksub << 4);
    Tf[((((long)kt * 8) + dt) * 64 + lf) * 8 + e] = f2bf(acc[dd]);
  }
}

// ===========================================================================
// 8-WAVE agg (512 thr, 2 waves/SIMD): BM=64 rows, wave (rw=w&3, dh=w>>2)
// owns rows rw*16..+15 x cols dh*64..+63. The second wave per SIMD hides
// the WAITV+barrier stall of the first. 4 VMEM/phase/wave -> WAITV(8).
// ===========================================================================

// ---------------------------------------------------------------------------
// FUSED agg layer 1: T1f = frag((relu(A @ T0)) @ W1)
// ---------------------------------------------------------------------------
__global__ __launch_bounds__(512, 1)
void agg_fused(const float* __restrict__ A, const short* __restrict__ Bf,
               const float* __restrict__ W1, short* __restrict__ T1f)
{
  __shared__ __align__(16) char sMem[131072];    // A: 4x16KB | B: 4x16KB
  char* sA = sMem;
  char* sB = sMem + 65536;

  const int tid  = threadIdx.x;
  const int lane = tid & 63;
  const int w    = tid >> 6;                     // wave 0..7
  const int rw   = w & 3;                        // row group
  const int dh   = w >> 2;                       // dt half
  const long rb  = (long)blockIdx.x * 64;
  const int arow = lane & 15;
  const int kgrp = lane >> 4;

  int rowi[2], colfi[2];
#pragma unroll
  for (int i = 0; i < 2; ++i) {
    const int o  = (2 * w + i) * 1024 + lane * 16;
    const int rr = o >> 8;
    const int cb = (o & 255) ^ ((rr & 7) << 4);
    rowi[i] = rr;
    colfi[i] = cb >> 2;
  }

  f32x4 acc[4];
#pragma unroll
  for (int j = 0; j < 4; ++j) acc[j] = (f32x4){0.f, 0.f, 0.f, 0.f};

  auto STAGE = [&](int buf, int t) {
#pragma unroll
    for (int i = 0; i < 2; ++i) {
      const float* g = A + (rb + rowi[i]) * (long)NN + t * BK + colfi[i];
      __builtin_amdgcn_global_load_lds(
          (const __attribute__((address_space(1))) unsigned int*)g,
          (__attribute__((address_space(3))) unsigned int*)(sA + buf * 16384 + (2 * w + i) * 1024),
          16, 0, 0x12);
    }
#pragma unroll
    for (int i = 0; i < 2; ++i) {
      const short* g = Bf + (long)t * 8192 + (2 * w + i) * 512 + lane * 8;
      __builtin_amdgcn_global_load_lds(
          (const __attribute__((address_space(1))) unsigned int*)g,
          (__attribute__((address_space(3))) unsigned int*)(sB + buf * 16384 + (2 * w + i) * 1024),
          16, 0, 0);
    }
  };

  auto COMPUTE = [&](int buf) {
    const char* la = sA + buf * 16384;
    const char* lb = sB + buf * 16384 + lane * 16;
    const int row = rw * 16 + arow;
    const int sw  = (arow & 7) << 4;
#pragma unroll
    for (int ks = 0; ks < 2; ++ks) {
      f32x4 a0 = *(const f32x4*)(la + row * 256 + ((ks * 128 + kgrp * 32) ^ sw));
      f32x4 a1 = *(const f32x4*)(la + row * 256 + ((ks * 128 + kgrp * 32 + 16) ^ sw));
      short8 af;
      af[0] = f2bf(a0.x); af[1] = f2bf(a0.y); af[2] = f2bf(a0.z); af[3] = f2bf(a0.w);
      af[4] = f2bf(a1.x); af[5] = f2bf(a1.y); af[6] = f2bf(a1.z); af[7] = f2bf(a1.w);
#pragma unroll
      for (int j = 0; j < 4; ++j) {
        short8 bf = *(const short8*)(lb + (ks * 8 + dh * 4 + j) * 1024);
        acc[j] = __builtin_amdgcn_mfma_f32_16x16x32_bf16(af, bf, acc[j], 0, 0, 0);
      }
    }
  };

  STAGE(0, 0); STAGE(1, 1); STAGE(2, 2);

  int t = 0;
  for (; t < NT - 4; t += 4) {
    WAITV(8); BAR(); STAGE(3, t + 3); COMPUTE(0);
    WAITV(8); BAR(); STAGE(0, t + 4); COMPUTE(1);
    WAITV(8); BAR(); STAGE(1, t + 5); COMPUTE(2);
    WAITV(8); BAR(); STAGE(2, t + 6); COMPUTE(3);
  }
  WAITV(8); BAR(); STAGE(3, t + 3); COMPUTE(0);
  WAITV(8); BAR(); COMPUTE(1);
  WAITV(4); BAR(); COMPUTE(2);
  WAITV(0); BAR(); COMPUTE(3);

  // ===== fused epilogue: T1 tile = relu(acc) @ W1 =====
  // 1) relu + transpose -> tbuf[rw] ([16][128] bf16, swizzle (row&15)<<4);
  //    dh-pair writes disjoint column halves.
  char* tbuf = sMem + rw * 4096;
#pragma unroll
  for (int j = 0; j < 4; ++j) {
#pragma unroll
    for (int r = 0; r < 4; ++r) {
      float v = acc[j][r];
      v = v > 0.f ? v : 0.f;
      const int rowl = kgrp * 4 + r;
      const int col  = (dh * 4 + j) * 16 + arow;
      const int byte = (rowl * 256 + col * 2) ^ ((rowl & 15) << 4);
      *(short*)(tbuf + byte) = f2bf(v);
    }
  }
  __syncthreads();

  // 2) stage W1 -> LDS bf16 B-frags (512 threads, 8 iters)
  {
    short* W1fL = (short*)(sMem + 98304);
    const float4* W14 = (const float4*)W1;
    for (int it = 0; it < 8; ++it) {
      const int lin = tid + it * 512;          // 0..4095
      const int j  = lin >> 5;                 // k-row 0..127
      const int d4 = lin & 31;
      float4 wv = W14[j * 32 + d4];
      float wa[4] = {wv.x, wv.y, wv.z, wv.w};
      const int ks = j >> 5, ksub = (j >> 3) & 3, e = j & 7;
#pragma unroll
      for (int c = 0; c < 4; ++c) {
        const int d = d4 * 4 + c;
        const int dt = d >> 4;
        const int lf = (d & 15) | (ksub << 4);
        W1fL[((ks * 8 + dt) * 64 + lf) * 8 + e] = f2bf(wa[c]);
      }
    }
  }
  __syncthreads();

  // 3) 16 MFMAs/wave: nacc = tbuf(A-frags of rw) x W1fL(dt-half dh)
  f32x4 nacc[4];
#pragma unroll
  for (int j = 0; j < 4; ++j) nacc[j] = (f32x4){0.f, 0.f, 0.f, 0.f};
  {
    const short* W1fL = (const short*)(sMem + 98304);
#pragma unroll
    for (int ks = 0; ks < 4; ++ks) {
      short8 af = *(const short8*)(tbuf +
          ((arow * 256 + (ks * 32 + kgrp * 8) * 2) ^ ((arow & 15) << 4)));
#pragma unroll
      for (int j = 0; j < 4; ++j) {
        short8 wf = *(const short8*)&W1fL[((ks * 8 + dh * 4 + j) * 64 + lane) * 8];
        nacc[j] = __builtin_amdgcn_mfma_f32_16x16x32_bf16(af, wf, nacc[j], 0, 0, 0);
      }
    }
  }

  // 4) assembly into B-frag-linear obuf (8 KB per kt), contiguous stores
  char* obuf = sMem + 65536 + (rw >> 1) * 8192;
  const int kh = rw & 1;
#pragma unroll
  for (int j = 0; j < 4; ++j) {
#pragma unroll
    for (int r = 0; r < 4; ++r) {
      const int dt = dh * 4 + j;
      const int kl = kh * 16 + kgrp * 4 + r;   // 0..31 within k-tile
      const int lf = arow | ((kl >> 3) << 4);
      const int e  = kl & 7;
      *(short*)(obuf + (dt * 512 + lf * 8 + e) * 2) = f2bf(nacc[j][r]);
    }
  }
  __syncthreads();
  {
    const long ktg = (long)blockIdx.x * 2 + (w >> 2);
    const char* obr = sMem + 65536 + ((w >> 2) & 1) * 8192;
#pragma unroll
    for (int i = 0; i < 2; ++i) {
      const int dt = (w & 3) * 2 + i;
      short8 vv = *(const short8*)(obr + (dt * 512 + lane * 8) * 2);
      *(short8*)(T1f + ((ktg * 8 + dt) * 64 + lane) * 8) = vv;
    }
  }
}

// ---------------------------------------------------------------------------
// agg layer 2 (8-wave): out = relu(A @ T1), fp32 out.
// ---------------------------------------------------------------------------
__global__ __launch_bounds__(512, 1)
void agg_kernel(const float* __restrict__ A, const short* __restrict__ Bf,
                float* __restrict__ out_)
{
  __shared__ __align__(16) char sMem[131072];
  char* sA = sMem;
  char* sB = sMem + 65536;

  const int tid  = threadIdx.x;
  const int lane = tid & 63;
  const int w    = tid >> 6;
  const int rw   = w & 3;
  const int dh   = w >> 2;
  const long rb  = (long)blockIdx.x * 64;
  const int arow = lane & 15;
  const int kgrp = lane >> 4;

  int rowi[2], colfi[2];
#pragma unroll
  for (int i = 0; i < 2; ++i) {
    const int o  = (2 * w + i) * 1024 + lane * 16;
    const int rr = o >> 8;
    const int cb = (o & 255) ^ ((rr & 7) << 4);
    rowi[i] = rr;
    colfi[i] = cb >> 2;
  }

  f32x4 acc[4];
#pragma unroll
  for (int j = 0; j < 4; ++j) acc[j] = (f32x4){0.f, 0.f, 0.f, 0.f};

  auto STAGE = [&](int buf, int t) {
#pragma unroll
    for (int i = 0; i < 2; ++i) {
      const float* g = A + (rb + rowi[i]) * (long)NN + t * BK + colfi[i];
      __builtin_amdgcn_global_load_lds(
          (const __attribute__((address_space(1))) unsigned int*)g,
          (__attribute__((address_space(3))) unsigned int*)(sA + buf * 16384 + (2 * w + i) * 1024),
          16, 0, 0x12);
    }
#pragma unroll
    for (int i = 0; i < 2; ++i) {
      const short* g = Bf + (long)t * 8192 + (2 * w + i) * 512 + lane * 8;
      __builtin_amdgcn_global_load_lds(
          (const __attribute__((address_space(1))) unsigned int*)g,
          (__attribute__((address_space(3))) unsigned int*)(sB + buf * 16384 + (2 * w + i) * 1024),
          16, 0, 0);
    }
  };

  auto COMPUTE = [&](int buf) {
    const char* la = sA + buf * 16384;
    const char* lb = sB + buf * 16384 + lane * 16;
    const int row = rw * 16 + arow;
    const int sw  = (arow & 7) << 4;
#pragma unroll
    for (int ks = 0; ks < 2; ++ks) {
      f32x4 a0 = *(const f32x4*)(la + row * 256 + ((ks * 128 + kgrp * 32) ^ sw));
      f32x4 a1 = *(const f32x4*)(la + row * 256 + ((ks * 128 + kgrp * 32 + 16) ^ sw));
      short8 af;
      af[0] = f2bf(a0.x); af[1] = f2bf(a0.y); af[2] = f2bf(a0.z); af[3] = f2bf(a0.w);
      af[4] = f2bf(a1.x); af[5] = f2bf(a1.y); af[6] = f2bf(a1.z); af[7] = f2bf(a1.w);
#pragma unroll
      for (int j = 0; j < 4; ++j) {
        short8 bf = *(const short8*)(lb + (ks * 8 + dh * 4 + j) * 1024);
        acc[j] = __builtin_amdgcn_mfma_f32_16x16x32_bf16(af, bf, acc[j], 0, 0, 0);
      }
    }
  };

  STAGE(0, 0); STAGE(1, 1); STAGE(2, 2);

  int t = 0;
  for (; t < NT - 4; t += 4) {
    WAITV(8); BAR(); STAGE(3, t + 3); COMPUTE(0);
    WAITV(8); BAR(); STAGE(0, t + 4); COMPUTE(1);
    WAITV(8); BAR(); STAGE(1, t + 5); COMPUTE(2);
    WAITV(8); BAR(); STAGE(2, t + 6); COMPUTE(3);
  }
  WAITV(8); BAR(); STAGE(3, t + 3); COMPUTE(0);
  WAITV(8); BAR(); COMPUTE(1);
  WAITV(4); BAR(); COMPUTE(2);
  WAITV(0); BAR(); COMPUTE(3);

#pragma unroll
  for (int j = 0; j < 4; ++j) {
#pragma unroll
    for (int r = 0; r < 4; ++r) {
      float v = acc[j][r];
      v = v > 0.f ? v : 0.f;
      const long row = rb + rw * 16 + kgrp * 4 + r;
      const int  col = (dh * 4 + j) * 16 + arow;
      __builtin_nontemporal_store(v, out_ + row * DD + col);
    }
  }
}

// ---------------------------------------------------------------------------
extern "C" void kernel_launch(void* const* d_in, const int* in_sizes, int n_in,
                              void* d_out, int out_size, void* d_ws, size_t ws_size,
                              hipStream_t stream)
{
  const float* A  = (const float*)d_in[0];   // [16384][16384]
  const float* X  = (const float*)d_in[1];   // [16384][128]
  const float* W0 = (const float*)d_in[2];   // [128][128]
  const float* W1 = (const float*)d_in[3];   // [128][128]

  short* T0f = (short*)d_ws;                 // bf16 fragment-major T0 (4 MB)
  short* T1f = T0f + (size_t)DD * NN;        // bf16 fragment-major T1 (4 MB)

  small_gemm<<<NN / 16, 256, 0, stream>>>(X, W0, T0f);
  agg_fused<<<NN / 64, 512, 0, stream>>>(A, T0f, W1, T1f);
  agg_kernel<<<NN / 64, 512, 0, stream>>>(A, T1f, (float*)d_out);
}